// Round 1
// baseline (1000.611 us; speedup 1.0000x reference)
//
#include <hip/hip_runtime.h>
#include <hip/hip_bf16.h>

#define IN_F 4096
#define OUT_F 11008

typedef __bf16 bf16_t;
typedef bf16_t bf16x8 __attribute__((ext_vector_type(8)));
typedef float f32x4 __attribute__((ext_vector_type(4)));

#define BM 128
#define BN 128
#define BK 32
#define LDP 48   // LDS row pitch in bf16 elements (96 B, 16B aligned)

__global__ __launch_bounds__(256, 2) void gptq_gemm_kernel(
    const float* __restrict__ x,
    const int*   __restrict__ qweight,
    const float* __restrict__ scales,
    const int*   __restrict__ qzeros,
    float* __restrict__ out)
{
    __shared__ bf16_t As[BM * LDP];
    __shared__ bf16_t Bs[BN * LDP];

    const int tid  = threadIdx.x;
    const int lane = tid & 63;
    const int wid  = tid >> 6;
    const int wr   = wid >> 1;      // 0..1
    const int wc   = wid & 1;       // 0..1

    const int m0 = blockIdx.y * BM;
    const int n0 = blockIdx.x * BN;

    // A staging map: item = tid + p*256 ; row = item>>2 (0..127), slot = item&3 (8 floats each)
    const int a_row  = tid >> 2;    // 0..63 (+64 on second pass)
    const int a_slot = tid & 3;
    // B staging map: item = tid + p*256 ; k8l = item>>7 (0..3), n = item&127
    const int b_k8l = tid >> 7;     // 0..1 (+2 on second pass)
    const int b_n   = tid & 127;

    f32x4 acc[4][4];
    #pragma unroll
    for (int i = 0; i < 4; ++i)
        #pragma unroll
        for (int j = 0; j < 4; ++j)
            acc[i][j] = (f32x4)0.0f;

    for (int kt = 0; kt < IN_F / BK; ++kt) {
        const int k0 = kt * BK;
        const int g  = k0 >> 7;     // GROUPSIZE=128

        __syncthreads();   // protect LDS from previous iteration's readers

        // ---- stage A: x[m0..+127][k0..+31] -> As (f32 -> bf16), 8 floats/thread/pass
        #pragma unroll
        for (int p = 0; p < 2; ++p) {
            const int row = a_row + p * 64;
            const float* src = x + (size_t)(m0 + row) * IN_F + k0 + a_slot * 8;
            f32x4 v0 = *(const f32x4*)src;
            f32x4 v1 = *(const f32x4*)(src + 4);
            bf16x8 h;
            h[0] = (bf16_t)v0[0]; h[1] = (bf16_t)v0[1];
            h[2] = (bf16_t)v0[2]; h[3] = (bf16_t)v0[3];
            h[4] = (bf16_t)v1[0]; h[5] = (bf16_t)v1[1];
            h[6] = (bf16_t)v1[2]; h[7] = (bf16_t)v1[3];
            *(bf16x8*)(&As[row * LDP + a_slot * 8]) = h;
        }

        // ---- stage B: dequant qweight rows k0/8..+3, cols n0..+127 -> Bs[n][k] (K-major)
        {
            const int n  = b_n;
            const int gn = n0 + n;
            const float s  = scales[(size_t)g * OUT_F + gn];
            const int   zw = qzeros[(size_t)g * (OUT_F / 8) + (gn >> 3)];
            const float z1 = (float)(((zw >> ((gn & 7) * 4)) & 0xF) + 1);
            const float sz = s * z1;
            #pragma unroll
            for (int p = 0; p < 2; ++p) {
                const int k8l = b_k8l + p * 2;   // 0..3
                const int w = qweight[(size_t)(k0 / 8 + k8l) * OUT_F + gn];
                bf16x8 h;
                #pragma unroll
                for (int j = 0; j < 8; ++j) {
                    const int q = (w >> (4 * j)) & 0xF;
                    h[j] = (bf16_t)fmaf((float)q, s, -sz);
                }
                *(bf16x8*)(&Bs[n * LDP + k8l * 8]) = h;
            }
        }

        __syncthreads();

        // ---- fragments + 16 MFMA (each covers the full BK=32)
        bf16x8 af[4], bfr[4];
        #pragma unroll
        for (int m = 0; m < 4; ++m) {
            const int row = wr * 64 + m * 16 + (lane & 15);
            af[m] = *(const bf16x8*)(&As[row * LDP + (lane >> 4) * 8]);
        }
        #pragma unroll
        for (int n = 0; n < 4; ++n) {
            const int col = wc * 64 + n * 16 + (lane & 15);
            bfr[n] = *(const bf16x8*)(&Bs[col * LDP + (lane >> 4) * 8]);
        }
        #pragma unroll
        for (int m = 0; m < 4; ++m)
            #pragma unroll
            for (int n = 0; n < 4; ++n)
                acc[m][n] = __builtin_amdgcn_mfma_f32_16x16x32_bf16(
                    af[m], bfr[n], acc[m][n], 0, 0, 0);
    }

    // ---- epilogue: C/D layout col = lane&15, row = (lane>>4)*4 + r  [m89-verified]
    const int cn  = lane & 15;
    const int cr4 = (lane >> 4) * 4;
    #pragma unroll
    for (int m = 0; m < 4; ++m) {
        #pragma unroll
        for (int r = 0; r < 4; ++r) {
            const int grow = m0 + wr * 64 + m * 16 + cr4 + r;
            float* orow = out + (size_t)grow * OUT_F + n0 + wc * 64 + cn;
            #pragma unroll
            for (int n = 0; n < 4; ++n)
                orow[n * 16] = acc[m][n][r];
        }
    }
}

extern "C" void kernel_launch(void* const* d_in, const int* in_sizes, int n_in,
                              void* d_out, int out_size, void* d_ws, size_t ws_size,
                              hipStream_t stream) {
    const float* x       = (const float*)d_in[0];
    const int*   qweight = (const int*)d_in[1];
    const float* scales  = (const float*)d_in[2];
    const int*   qzeros  = (const int*)d_in[3];
    float* out = (float*)d_out;

    const int M = in_sizes[0] / IN_F;          // 4*2048 = 8192
    dim3 grid(OUT_F / BN, M / BM);             // (86, 64)
    dim3 block(256);
    gptq_gemm_kernel<<<grid, block, 0, stream>>>(x, qweight, scales, qzeros, out);
}